// Round 10
// baseline (1125.984 us; speedup 1.0000x reference)
//
#include <hip/hip_runtime.h>

// ---------------------------------------------------------------------------
// Bidirectional GRU (B=128, T=512, E=H=256) + linear head.
// Phase 1: LDS-shared wide-N gate table + LDS-transpose epilogue so G is
//          written as contiguous 1536 B row bursts (was 2 B scatter).
// Phase 2: R6 recurrence core (16 WGs x 512 thr, W_hh in 192 regs, l-split)
//          with xg gathered DIRECTLY into 12 VGPRs one step ahead and
//          xr/xz folded into MFMA C-init from registers (no LDS staging).
// ---------------------------------------------------------------------------

typedef float f32x4 __attribute__((ext_vector_type(4)));
typedef short s16x8 __attribute__((ext_vector_type(8)));

#define VOCAB   30000
#define GCOLS   1536
#define HB_STR  280     // bf16 elems per h/emb row (560 B)
#define HBUF    (16 * HB_STR)
#define CS_STR  776     // bf16 elems per cS row (1552 B, 16B-aligned)
#define HS_STR  260     // f32 elems per h row for epilogue
#define SRF     (-1.4426950408889634f)   // -log2(e), sigmoid gates
#define SNF     (2.8853900817779268f)    // 2*log2(e), tanh gate

#if defined(__has_builtin)
#if __has_builtin(__builtin_amdgcn_cvt_pk_bf16_f32)
#define HAVE_PK 1
#endif
#endif

static __device__ __forceinline__ unsigned short f2bf(float f) {
    unsigned u = __builtin_bit_cast(unsigned, f);
    u += 0x7fffu + ((u >> 16) & 1u);            // RNE
    return (unsigned short)(u >> 16);
}
#ifdef HAVE_PK
typedef __bf16 bf16x2_t __attribute__((ext_vector_type(2)));
static __device__ __forceinline__ unsigned pk2(float a, float b) {
    bf16x2_t v = __builtin_amdgcn_cvt_pk_bf16_f32(a, b);
    return __builtin_bit_cast(unsigned, v);
}
#else
static __device__ __forceinline__ unsigned pk2(float a, float b) {
    return (unsigned)f2bf(a) | ((unsigned)f2bf(b) << 16);
}
#endif
static __device__ __forceinline__ float bf_lo(unsigned v) {
    return __builtin_bit_cast(float, v << 16);
}
static __device__ __forceinline__ float bf_hi(unsigned v) {
    return __builtin_bit_cast(float, v & 0xffff0000u);
}
static __device__ __forceinline__ s16x8 pack_bf8(float4 a, float4 b, float s) {
    union { s16x8 v; unsigned u[4]; } r;
    r.u[0] = pk2(a.x * s, a.y * s); r.u[1] = pk2(a.z * s, a.w * s);
    r.u[2] = pk2(b.x * s, b.y * s); r.u[3] = pk2(b.z * s, b.w * s);
    return r.v;
}
static __device__ __forceinline__ f32x4 mfma16(s16x8 a, s16x8 b, f32x4 c) {
    return __builtin_amdgcn_mfma_f32_16x16x32_bf16(a, b, c, 0, 0, 0);
}
static __device__ __forceinline__ float sig2(float x) {      // 1/(1+2^x)
    return __builtin_amdgcn_rcpf(1.0f + __builtin_amdgcn_exp2f(x));
}

// permuted col c = d*768 + (6*w8+t)*16 + u; orig gate row =
// (t>>1)*256 + 32*w8 + ((t&1)<<4) + u;  t in {0,1}=r, {2,3}=z, {4,5}=n.

// ---------------------------------------------------------------------------
// Phase 1: gate table.  grid (2 dirs, 128 M-slices), 512 threads.
// ---------------------------------------------------------------------------
__global__ __launch_bounds__(512, 2)
void gru_table_kernel(const float* __restrict__ emb,
                      const float* __restrict__ Wih_f, const float* __restrict__ bih_f,
                      const float* __restrict__ bhh_f,
                      const float* __restrict__ Wih_b, const float* __restrict__ bih_b,
                      const float* __restrict__ bhh_b,
                      unsigned short* __restrict__ G) {
    __shared__ unsigned short aS[2][16 * HB_STR];    // dbuf emb tile (bf16)
    __shared__ unsigned short cS[16][CS_STR];        // out tile (row-major)

    const int tid  = threadIdx.x;
    const int lane = tid & 63;
    const int w    = tid >> 6;       // wave 0..7 -> N-tiles 6w..6w+5
    const int u    = lane & 15;
    const int q    = lane >> 4;
    const int d    = blockIdx.x;     // 0 fwd, 1 bwd
    const int by   = blockIdx.y;     // 0..127

    const float* Wih = d ? Wih_b : Wih_f;
    const float* bih = d ? bih_b : bih_f;
    const float* bhh = d ? bhh_b : bhh_f;

    // 6 N-tiles per wave, weights register-resident (192 regs).
    s16x8 breg[48];
    float beta[6];
#pragma unroll
    for (int t = 0; t < 6; ++t) {
        const int orig = (t >> 1) * 256 + 32 * w + ((t & 1) << 4) + u;
        const float scl = (t < 4) ? SRF : SNF;
        beta[t] = (bih[orig] + ((t < 4) ? bhh[orig] : 0.0f)) * scl;
#pragma unroll
        for (int kt = 0; kt < 8; ++kt) {
            const float* p = Wih + orig * 256 + kt * 32 + q * 8;
            breg[t * 8 + kt] =
                pack_bf8(*(const float4*)p, *(const float4*)(p + 4), scl);
        }
    }

    // staging coords: thread -> (row, col8) of a 16x256 tile
    const int srow = tid >> 5;
    const int sc8  = (tid & 31) * 8;
    // store coords: thread -> (row, 24-col chunk) of the 16x768 out tile
    const int orow = tid >> 5;
    const int oc0  = (tid & 31) * 24;

    // prologue: stage tile `by` into buf 0
    {
        const float* p = emb + (size_t)(by * 16 + srow) * 256 + sc8;
        float4 e0 = *(const float4*)p, e1 = *(const float4*)(p + 4);
        unsigned* dp = (unsigned*)&aS[0][srow * HB_STR + sc8];
        dp[0] = pk2(e0.x, e0.y); dp[1] = pk2(e0.z, e0.w);
        dp[2] = pk2(e1.x, e1.y); dp[3] = pk2(e1.z, e1.w);
    }
    __syncthreads();

    for (int i = 0;; ++i) {
        const int mt = by + i * 128;
        if (mt >= 1875) break;
        const int mtn = mt + 128;
        const bool has_next = (mtn < 1875);
        const int buf = i & 1;

        // issue next tile's global loads early (waitcnt lands after MFMAs)
        float4 e0, e1;
        if (has_next) {
            const float* p = emb + (size_t)(mtn * 16 + srow) * 256 + sc8;
            e0 = *(const float4*)p;
            e1 = *(const float4*)(p + 4);
        }

        // two halves (l = lo/hi 16-block): 3 accs live, LDS af per kt
#pragma unroll
        for (int l = 0; l < 2; ++l) {
            f32x4 a0 = {0.f, 0.f, 0.f, 0.f}, a1 = a0, a2 = a0;
#pragma unroll
            for (int kt = 0; kt < 8; ++kt) {
                s16x8 af = *(const s16x8*)&aS[buf][u * HB_STR + kt * 32 + q * 8];
                a0 = mfma16(af, breg[(0 + l) * 8 + kt], a0);
                a1 = mfma16(af, breg[(2 + l) * 8 + kt], a1);
                a2 = mfma16(af, breg[(4 + l) * 8 + kt], a2);
            }
#pragma unroll
            for (int g = 0; g < 3; ++g) {
                const f32x4 a = (g == 0) ? a0 : (g == 1) ? a1 : a2;
                const int t = 2 * g + l;
#pragma unroll
                for (int r = 0; r < 4; ++r)
                    cS[q * 4 + r][(6 * w + t) * 16 + u] = f2bf(a[r] + beta[t]);
            }
        }
        __syncthreads();   // cS complete; all waves done reading aS[buf]

        // coalesced G stores: 1536 B contiguous per row
        {
            const uint4* sp = (const uint4*)&cS[orow][oc0];
            uint4 v0 = sp[0], v1 = sp[1], v2 = sp[2];
            uint4* dp = (uint4*)(G + (size_t)(mt * 16 + orow) * GCOLS + d * 768 + oc0);
            dp[0] = v0; dp[1] = v1; dp[2] = v2;
        }
        // stage next tile into the other buffer
        if (has_next) {
            unsigned* dp = (unsigned*)&aS[buf ^ 1][srow * HB_STR + sc8];
            dp[0] = pk2(e0.x, e0.y); dp[1] = pk2(e0.z, e0.w);
            dp[2] = pk2(e1.x, e1.y); dp[3] = pk2(e1.z, e1.w);
        }
        __syncthreads();   // aS[buf^1] ready; cS reusable
    }
}

// ---------------------------------------------------------------------------
// Phase 2: recurrence. grid = 16 (dir = bx>>3, batch group = bx&7), 512 thr.
// xg prefetched into 12 VGPRs one step ahead; xr/xz folded into C-init.
// ---------------------------------------------------------------------------
__global__ __launch_bounds__(512, 2)
void gru_rnn_kernel(const int* __restrict__ inp,
                    const float* __restrict__ Whh_f, const float* __restrict__ bhh_f,
                    const float* __restrict__ Whh_b, const float* __restrict__ bhh_b,
                    const float* __restrict__ W_lin, const float* __restrict__ b_lin,
                    const unsigned short* __restrict__ G,
                    float* __restrict__ out) {
    __shared__ int            toks[16][513];          // tok*GCOLS offsets
    __shared__ unsigned short hB[2 * HBUF];           // dbuf h (bf16)
    __shared__ float          bhnS[256];
    __shared__ float          hs[16 * HS_STR];        // epilogue

    const int tid  = threadIdx.x;
    const int lane = tid & 63;
    const int w    = tid >> 6;          // wave 0..7 (owns i in [32w,32w+32))
    const int b    = lane & 15;         // batch within group
    const int q    = lane >> 4;
    const int d    = blockIdx.x >> 3;   // 0 fwd, 1 bwd
    const int b0   = (blockIdx.x & 7) * 16;

    const float* Whh = d ? Whh_b : Whh_f;
    const float* bhh = d ? bhh_b : bhh_f;

    // W_hh as 48 A-fragments (pre-scaled): tile t = 2*gate + half.  192 regs.
    s16x8 wreg[48];
#pragma unroll
    for (int t = 0; t < 6; ++t) {
        const int orig = (t >> 1) * 256 + 32 * w + ((t & 1) << 4) + b;
        const float scl = (t < 4) ? SRF : SNF;
#pragma unroll
        for (int kt = 0; kt < 8; ++kt) {
            const float* p = Whh + orig * 256 + kt * 32 + q * 8;
            wreg[t * 8 + kt] =
                pack_bf8(*(const float4*)p, *(const float4*)(p + 4), scl);
        }
    }

    for (int i = tid; i < 16 * 512; i += 512) {
        int bb = i >> 9, t = i & 511;
        toks[bb][t] = inp[(b0 + bb) * 512 + t] * GCOLS;   // pre-scaled
    }
    for (int i = tid; i < 2 * HBUF; i += 512) hB[i] = 0;   // h0 = 0
    if (tid < 256) bhnS[tid] = SNF * bhh[512 + tid];
    __syncthreads();

    const int gcol = d * 768 + 96 * w + 4 * q;   // this lane's xg col base
    const int hbq  = b * HB_STR + q * 8;
    float hreg[8];
#pragma unroll
    for (int i = 0; i < 8; ++i) hreg[i] = 0.f;

    // prologue: direct prefetch of step-0 xg (6 x 8 B per lane, 12 VGPRs)
    uint2 pxr0, pxr1, pxz0, pxz1, pxn0, pxn1;
    {
        const uint2* gp = (const uint2*)(G + toks[b][d ? 511 : 0] + gcol);
        pxr0 = gp[0];  pxr1 = gp[4];
        pxz0 = gp[8];  pxz1 = gp[12];
        pxn0 = gp[16]; pxn1 = gp[20];
    }

#pragma unroll 2
    for (int ts = 0; ts < 512; ++ts) {
        const int rb = (ts & 1) * HBUF;
        const int pn = (ts + 1) & 1;
        int s1 = (ts < 511) ? ts + 1 : 511;
        const int t1 = d ? 511 - s1 : s1;

        // two column-halves: xr/xz folded into C-init from registers
#pragma unroll
        for (int l = 0; l < 2; ++l) {
            const uint2 uxr = l ? pxr1 : pxr0;
            const uint2 uxz = l ? pxz1 : pxz0;
            const uint2 uxn = l ? pxn1 : pxn0;
            f32x4 ar = {bf_lo(uxr.x), bf_hi(uxr.x), bf_lo(uxr.y), bf_hi(uxr.y)};
            f32x4 az = {bf_lo(uxz.x), bf_hi(uxz.x), bf_lo(uxz.y), bf_hi(uxz.y)};
            f32x4 an = *(const f32x4*)&bhnS[32 * w + 16 * l + 4 * q];
            float xn[4] = {bf_lo(uxn.x), bf_hi(uxn.x), bf_lo(uxn.y), bf_hi(uxn.y)};
            if (l == 1) {   // all 6 prefetch regs consumed -> issue next gather
                const uint2* gp = (const uint2*)(G + toks[b][t1] + gcol);
                pxr0 = gp[0];  pxr1 = gp[4];
                pxz0 = gp[8];  pxz1 = gp[12];
                pxn0 = gp[16]; pxn1 = gp[20];
            }
#pragma unroll
            for (int kt = 0; kt < 8; ++kt) {
                s16x8 hf = *(const s16x8*)&hB[rb + hbq + kt * 32];
                ar = mfma16(wreg[(0 + l) * 8 + kt], hf, ar);
                az = mfma16(wreg[(2 + l) * 8 + kt], hf, az);
                an = mfma16(wreg[(4 + l) * 8 + kt], hf, an);
            }
#pragma unroll
            for (int r = 0; r < 4; ++r) {
                float rg = sig2(ar[r]);
                float zg = sig2(az[r]);
                float tg = sig2(fmaf(rg, an[r], xn[r]));
                float ng = fmaf(-2.0f, tg, 1.0f);
                const int i = l * 4 + r;
                hreg[i] = fmaf(zg, hreg[i] - ng, ng);
            }
            // write this half's h_new (bf16) to the other h buffer
            unsigned p0 = pk2(hreg[l * 4 + 0], hreg[l * 4 + 1]);
            unsigned p1 = pk2(hreg[l * 4 + 2], hreg[l * 4 + 3]);
            *(uint2*)&hB[pn * HBUF + b * HB_STR + 32 * w + 16 * l + 4 * q] =
                make_uint2(p0, p1);
        }
        __syncthreads();   // h_new visible; xg prefetch stays covered
    }

    // epilogue: out[b][c] += h_d[b] . W_lin[c, d*256:+256]  (+ b_lin once)
#pragma unroll
    for (int l = 0; l < 2; ++l) {
        f32x4 v = {hreg[l * 4 + 0], hreg[l * 4 + 1],
                   hreg[l * 4 + 2], hreg[l * 4 + 3]};
        *(f32x4*)&hs[b * HS_STR + 32 * w + 16 * l + 4 * q] = v;
    }
    __syncthreads();
    if (tid < 160) {
        int bb = tid / 10;
        int c  = tid - bb * 10;
        float acc = d ? 0.0f : b_lin[c];
        const float* wl = W_lin + c * 512 + d * 256;
        const float* hp = &hs[bb * HS_STR];
        for (int i = 0; i < 256; ++i) acc += hp[i] * wl[i];
        atomicAdd(&out[(b0 + bb) * 10 + c], acc);
    }
}

// ---------------------------------------------------------------------------
extern "C" void kernel_launch(void* const* d_in, const int* in_sizes, int n_in,
                              void* d_out, int out_size, void* d_ws, size_t ws_size,
                              hipStream_t stream) {
    const int*   inp   = (const int*)d_in[0];
    const float* emb   = (const float*)d_in[1];
    const float* Wih_f = (const float*)d_in[2];
    const float* Whh_f = (const float*)d_in[3];
    const float* bih_f = (const float*)d_in[4];
    const float* bhh_f = (const float*)d_in[5];
    const float* Wih_b = (const float*)d_in[6];
    const float* Whh_b = (const float*)d_in[7];
    const float* bih_b = (const float*)d_in[8];
    const float* bhh_b = (const float*)d_in[9];
    const float* W_lin = (const float*)d_in[10];
    const float* b_lin = (const float*)d_in[11];
    float* out = (float*)d_out;
    unsigned short* G = (unsigned short*)d_ws;   // 30000*1536*2 B = 92.16 MB

    hipMemsetAsync(d_out, 0, (size_t)out_size * sizeof(float), stream);
    hipLaunchKernelGGL(gru_table_kernel, dim3(2, 128), dim3(512), 0, stream,
                       emb, Wih_f, bih_f, bhh_f, Wih_b, bih_b, bhh_b, G);
    hipLaunchKernelGGL(gru_rnn_kernel, dim3(16), dim3(512), 0, stream,
                       inp, Whh_f, bhh_f, Whh_b, bhh_b, W_lin, b_lin, G, out);
}